// Round 2
// baseline (365.730 us; speedup 1.0000x reference)
//
#include <hip/hip_runtime.h>
#include <hip/hip_bf16.h>
#include <math.h>

#define LSEQ 2048
#define HD   512
#define NST  32
#define LC   64
#define NCHK 32   /* LSEQ/LC */
#define HH   (HD * HD)

typedef __bf16 bf16;
typedef __bf16 bf16x8 __attribute__((ext_vector_type(8)));
typedef float  floatx4 __attribute__((ext_vector_type(4)));

__device__ __forceinline__ float wave_reduce_add(float v) {
#pragma unroll
    for (int m = 32; m; m >>= 1) v += __shfl_xor(v, m, 64);
    return v;
}

__device__ __forceinline__ float gelu_tanh(float x) {
    float z = 0.7978845608028654f * (x + 0.044715f * x * x * x);
    float e = __expf(2.f * z);
    float th = 1.f - 2.f / (e + 1.f);   // tanh(z), saturates cleanly at e=inf
    return 0.5f * x * (1.f + th);
}

__device__ __forceinline__ void make_ab(float lre, float lim, float step,
                                        float br0, float bi0,
                                        float& ar, float& ai, float& br, float& bi) {
    float s2 = 0.5f * step;
    float dr = 1.f - s2 * lre, di = -s2 * lim;      // 1 - (dt/2)Lam
    float inv = 1.f / (dr * dr + di * di);
    float blr = dr * inv, bli = -di * inv;          // BL = 1/(dr+i*di)
    float nr = 1.f + s2 * lre, ni = s2 * lim;       // 1 + (dt/2)Lam
    ar = blr * nr - bli * ni;
    ai = blr * ni + bli * nr;
    float tr = step * br0, ti = step * bi0;         // dt * B
    br = blr * tr - bli * ti;
    bi = blr * ti + bli * tr;
}

// ---------------- weight f32 -> bf16 conversion (out_w / out2_w) ----------------
__global__ __launch_bounds__(256) void cvt_kernel(
    const float* __restrict__ ow, const float* __restrict__ o2w,
    bf16* __restrict__ wb) {
    const float* src = blockIdx.y ? o2w : ow;
    bf16* dst = wb + blockIdx.y * (4 * HH);
    int i = (blockIdx.x * 256 + threadIdx.x) * 8;
    float4 a = *(const float4*)(src + i);
    float4 b = *(const float4*)(src + i + 4);
    bf16x8 o;
    o[0] = (bf16)a.x; o[1] = (bf16)a.y; o[2] = (bf16)a.z; o[3] = (bf16)a.w;
    o[4] = (bf16)b.x; o[5] = (bf16)b.y; o[6] = (bf16)b.z; o[7] = (bf16)b.w;
    *(bf16x8*)(dst + i) = o;
}

// ---------------- encoder: h[L,H] = x[L,4] @ enc_w.T + enc_b ----------------
__global__ __launch_bounds__(256) void enc_kernel(
    const float* __restrict__ x, const float* __restrict__ w,
    const float* __restrict__ b, float* __restrict__ h) {
    int idx = blockIdx.x * 256 + threadIdx.x;   // t*HD + i
    int t = idx >> 9, i = idx & (HD - 1);
    float acc = b[i];
    float4 xv = *(const float4*)(x + t * 4);
    float4 wv = *(const float4*)(w + i * 4);
    acc = fmaf(xv.x, wv.x, acc);
    acc = fmaf(xv.y, wv.y, acc);
    acc = fmaf(xv.z, wv.z, acc);
    acc = fmaf(xv.w, wv.w, acc);
    h[idx] = acc;
}

// ---------------- LayerNorm: one wave per row ----------------
__global__ __launch_bounds__(256) void ln_kernel(
    const float* __restrict__ h, float* __restrict__ hn,
    const float* __restrict__ w, const float* __restrict__ b) {
    int wv = threadIdx.x >> 6, lane = threadIdx.x & 63;
    int row = blockIdx.x * 4 + wv;
    const float* hp = h + row * HD + lane * 8;
    float v[8];
    *(float4*)(v)     = *(const float4*)(hp);
    *(float4*)(v + 4) = *(const float4*)(hp + 4);
    float s = 0.f;
#pragma unroll
    for (int e = 0; e < 8; ++e) s += v[e];
    s = wave_reduce_add(s);
    float m = s * (1.f / HD);
    float q = 0.f;
#pragma unroll
    for (int e = 0; e < 8; ++e) { float d = v[e] - m; q += d * d; }
    q = wave_reduce_add(q);
    float rstd = rsqrtf(q * (1.f / HD) + 1e-5f);
    float w8[8], b8[8];
    *(float4*)(w8)     = *(const float4*)(w + lane * 8);
    *(float4*)(w8 + 4) = *(const float4*)(w + lane * 8 + 4);
    *(float4*)(b8)     = *(const float4*)(b + lane * 8);
    *(float4*)(b8 + 4) = *(const float4*)(b + lane * 8 + 4);
    float o[8];
#pragma unroll
    for (int e = 0; e < 8; ++e)
        o[e] = (v[e] - m) * rstd * w8[e] + b8[e];
    float* op = hn + row * HD + lane * 8;
    *(float4*)op       = *(float4*)o;
    *(float4*)(op + 4) = *(float4*)(o + 4);
}

// ---------------- P1: per-chunk local final states (zero init) ----------------
// lane owns channel ch = bx*32 + tid>>3, states n = (tid&7) + {0,8,16,24}
__global__ __launch_bounds__(256) void p1_kernel(
    const float* __restrict__ u,
    const float* __restrict__ lre_p, const float* __restrict__ lim_p,
    const float* __restrict__ bre_p, const float* __restrict__ bim_p,
    const float* __restrict__ lstep_p,
    float2* __restrict__ f) {
    int ch = blockIdx.x * 32 + (threadIdx.x >> 3);
    int sub = threadIdx.x & 7;
    int chunk = blockIdx.y;
    float step = __expf(lstep_p[ch]);
    float ar[4], ai[4], br[4], bi[4], sr[4] = {0,0,0,0}, si[4] = {0,0,0,0};
#pragma unroll
    for (int j = 0; j < 4; ++j) {
        int idx = ch * NST + sub + 8 * j;
        make_ab(lre_p[idx], lim_p[idx], step,
                bre_p[idx], bim_p[idx], ar[j], ai[j], br[j], bi[j]);
    }
    const float* up = u + chunk * LC * HD + ch;
#pragma unroll 4
    for (int t = 0; t < LC; ++t) {
        float uu = up[t * HD];
#pragma unroll
        for (int j = 0; j < 4; ++j) {
            float nr = fmaf(ar[j], sr[j], fmaf(-ai[j], si[j], br[j] * uu));
            float ni = fmaf(ai[j], sr[j], fmaf( ar[j], si[j], bi[j] * uu));
            sr[j] = nr; si[j] = ni;
        }
    }
#pragma unroll
    for (int j = 0; j < 4; ++j)
        f[(chunk * HD + ch) * NST + sub + 8 * j] = make_float2(sr[j], si[j]);
}

// ---------------- P3: combine chunk inits in-register, replay chunk, emit gelu(y) as bf16 ----------------
__global__ __launch_bounds__(256) void p3_kernel(
    const float* __restrict__ u, const float2* __restrict__ f,
    const float* __restrict__ lre_p, const float* __restrict__ lim_p,
    const float* __restrict__ bre_p, const float* __restrict__ bim_p,
    const float* __restrict__ cre_p, const float* __restrict__ cim_p,
    const float* __restrict__ d_p,   const float* __restrict__ lstep_p,
    bf16* __restrict__ g) {
    int ch = blockIdx.x * 32 + (threadIdx.x >> 3);
    int sub = threadIdx.x & 7;
    int chunk = blockIdx.y;
    float step = __expf(lstep_p[ch]);
    float dch = d_p[ch];
    float ar[4], ai[4], br[4], bi[4], cr[4], ci[4];
#pragma unroll
    for (int j = 0; j < 4; ++j) {
        int idx = ch * NST + sub + 8 * j;
        make_ab(lre_p[idx], lim_p[idx], step,
                bre_p[idx], bim_p[idx], ar[j], ai[j], br[j], bi[j]);
        cr[j] = cre_p[idx];
        ci[j] = cim_p[idx];
    }
    // a^64 per state (6 squarings)
    float pr[4], pi[4];
#pragma unroll
    for (int j = 0; j < 4; ++j) {
        float xr = ar[j], xi = ai[j];
#pragma unroll
        for (int q = 0; q < 6; ++q) { float tt = xr * xr - xi * xi; xi = 2.f * xr * xi; xr = tt; }
        pr[j] = xr; pi[j] = xi;
    }
    // chunk-initial state: S = sum_{c<chunk} a64^{chunk-1-c} f[c]
    float sr[4] = {0,0,0,0}, si[4] = {0,0,0,0};
    for (int c = 0; c < chunk; ++c) {
#pragma unroll
        for (int j = 0; j < 4; ++j) {
            float2 fv = f[(c * HD + ch) * NST + sub + 8 * j];
            float nr = fmaf(pr[j], sr[j], fmaf(-pi[j], si[j], fv.x));
            float ni = fmaf(pi[j], sr[j], fmaf( pr[j], si[j], fv.y));
            sr[j] = nr; si[j] = ni;
        }
    }
    const float* up = u + chunk * LC * HD + ch;
    bf16* gp = g + chunk * LC * HD + ch;
#pragma unroll 4
    for (int t = 0; t < LC; ++t) {
        float uu = up[t * HD];
        float p = 0.f;
#pragma unroll
        for (int j = 0; j < 4; ++j) {
            float nr = fmaf(ar[j], sr[j], fmaf(-ai[j], si[j], br[j] * uu));
            float ni = fmaf(ai[j], sr[j], fmaf( ar[j], si[j], bi[j] * uu));
            sr[j] = nr; si[j] = ni;
            p = fmaf(cr[j], nr, fmaf(-ci[j], ni, p));
        }
        p += __shfl_xor(p, 1);
        p += __shfl_xor(p, 2);
        p += __shfl_xor(p, 4);
        if (sub == 0) {
            float y = fmaf(dch, uu, 2.f * p);
            gp[t * HD] = (bf16)gelu_tanh(y);
        }
    }
}

// ---------------- fused gated dual-matmul + residual ----------------
// hnew[t,j] = h[t,j] + (g@ow.T + ob) * sigmoid(g@o2w.T + o2b)
__global__ __launch_bounds__(256) void mm_kernel(
    const bf16* __restrict__ A,    // g [L,H] bf16
    const bf16* __restrict__ W1,   // out_w  [H,H] (n,k) bf16
    const bf16* __restrict__ W2,   // out2_w [H,H] bf16
    const float* __restrict__ bias1, const float* __restrict__ bias2,
    float* __restrict__ Hio) {
    const int w = threadIdx.x >> 6, lane = threadIdx.x & 63;
    const int wm = w >> 1, wn = w & 1;
    const int mBase = blockIdx.y * 64 + wm * 32;
    const int nBase = blockIdx.x * 64 + wn * 32;
    const int lrow = lane & 15, quad = lane >> 4;

    floatx4 acc1[2][2] = {{{0.f,0.f,0.f,0.f},{0.f,0.f,0.f,0.f}},{{0.f,0.f,0.f,0.f},{0.f,0.f,0.f,0.f}}};
    floatx4 acc2[2][2] = {{{0.f,0.f,0.f,0.f},{0.f,0.f,0.f,0.f}},{{0.f,0.f,0.f,0.f},{0.f,0.f,0.f,0.f}}};

    for (int k0 = 0; k0 < HD; k0 += 32) {
        int kk = k0 + quad * 8;
        bf16x8 a0 = *(const bf16x8*)(A + (mBase + lrow) * HD + kk);
        bf16x8 a1 = *(const bf16x8*)(A + (mBase + 16 + lrow) * HD + kk);
        bf16x8 p0 = *(const bf16x8*)(W1 + (nBase + lrow) * HD + kk);
        bf16x8 p1 = *(const bf16x8*)(W1 + (nBase + 16 + lrow) * HD + kk);
        bf16x8 q0 = *(const bf16x8*)(W2 + (nBase + lrow) * HD + kk);
        bf16x8 q1 = *(const bf16x8*)(W2 + (nBase + 16 + lrow) * HD + kk);
        acc1[0][0] = __builtin_amdgcn_mfma_f32_16x16x32_bf16(a0, p0, acc1[0][0], 0, 0, 0);
        acc1[0][1] = __builtin_amdgcn_mfma_f32_16x16x32_bf16(a0, p1, acc1[0][1], 0, 0, 0);
        acc1[1][0] = __builtin_amdgcn_mfma_f32_16x16x32_bf16(a1, p0, acc1[1][0], 0, 0, 0);
        acc1[1][1] = __builtin_amdgcn_mfma_f32_16x16x32_bf16(a1, p1, acc1[1][1], 0, 0, 0);
        acc2[0][0] = __builtin_amdgcn_mfma_f32_16x16x32_bf16(a0, q0, acc2[0][0], 0, 0, 0);
        acc2[0][1] = __builtin_amdgcn_mfma_f32_16x16x32_bf16(a0, q1, acc2[0][1], 0, 0, 0);
        acc2[1][0] = __builtin_amdgcn_mfma_f32_16x16x32_bf16(a1, q0, acc2[1][0], 0, 0, 0);
        acc2[1][1] = __builtin_amdgcn_mfma_f32_16x16x32_bf16(a1, q1, acc2[1][1], 0, 0, 0);
    }

#pragma unroll
    for (int fm = 0; fm < 2; ++fm)
#pragma unroll
        for (int fn = 0; fn < 2; ++fn) {
            int j = nBase + fn * 16 + lrow;
            float bb1 = bias1[j], bb2 = bias2[j];
#pragma unroll
            for (int r = 0; r < 4; ++r) {
                int t = mBase + fm * 16 + quad * 4 + r;
                float z1 = acc1[fm][fn][r] + bb1;
                float z2 = acc2[fm][fn][r] + bb2;
                float val = z1 / (1.f + __expf(-z2));
                Hio[t * HD + j] += val;
            }
        }
}

// ---------------- decoder: out[L,3] ----------------
__global__ __launch_bounds__(192) void dec_kernel(
    const float* __restrict__ h, const float* __restrict__ w,
    const float* __restrict__ b, float* __restrict__ out) {
    int j = threadIdx.x >> 6, lane = threadIdx.x & 63;
    int t = blockIdx.x;
    const float* hp = h + t * HD + lane * 8;
    float v[8];
    *(float4*)(v)     = *(const float4*)(hp);
    *(float4*)(v + 4) = *(const float4*)(hp + 4);
    float w8[8];
    *(float4*)(w8)     = *(const float4*)(w + j * HD + lane * 8);
    *(float4*)(w8 + 4) = *(const float4*)(w + j * HD + lane * 8 + 4);
    float s = 0.f;
#pragma unroll
    for (int e = 0; e < 8; ++e) s = fmaf(v[e], w8[e], s);
    s = wave_reduce_add(s);
    if (lane == 0) out[t * 3 + j] = s + b[j];
}

extern "C" void kernel_launch(void* const* d_in, const int* in_sizes, int n_in,
                              void* d_out, int out_size, void* d_ws, size_t ws_size,
                              hipStream_t stream) {
    const float* x   = (const float*)d_in[0];
    const float* ew  = (const float*)d_in[1];
    const float* eb  = (const float*)d_in[2];
    const float* dw  = (const float*)d_in[3];
    const float* db  = (const float*)d_in[4];
    const float* nw  = (const float*)d_in[5];
    const float* nb  = (const float*)d_in[6];
    const float* lre = (const float*)d_in[7];
    const float* lim = (const float*)d_in[8];
    const float* bre = (const float*)d_in[9];
    const float* bim = (const float*)d_in[10];
    const float* cre = (const float*)d_in[11];
    const float* cim = (const float*)d_in[12];
    const float* dd  = (const float*)d_in[13];
    const float* ls  = (const float*)d_in[14];
    const float* ow  = (const float*)d_in[15];
    const float* ob  = (const float*)d_in[16];
    const float* o2w = (const float*)d_in[17];
    const float* o2b = (const float*)d_in[18];

    char* ws = (char*)d_ws;
    float*  h  = (float*)ws;                   // 4 MB  [L,H]
    float*  hn = (float*)(ws + (4 << 20));     // 4 MB  [L,H]
    float2* f  = (float2*)(ws + (8 << 20));    // 4 MB  [NCHK,H,NST]
    bf16*   g  = (bf16*)(ws + (12 << 20));     // 2 MB  [L,H] bf16
    bf16*   wb = (bf16*)(ws + (14 << 20));     // 4 MB  bf16 out_w(4 layers) then out2_w(4 layers)

    cvt_kernel<<<dim3(4 * HH / (256 * 8), 2), 256, 0, stream>>>(ow, o2w, wb);
    enc_kernel<<<LSEQ * HD / 256, 256, 0, stream>>>(x, ew, eb, h);
    for (int lay = 0; lay < 4; ++lay) {
        int oHN = lay * HD * NST, oH = lay * HD;
        ln_kernel<<<LSEQ / 4, 256, 0, stream>>>(h, hn, nw + oH, nb + oH);
        p1_kernel<<<dim3(HD / 32, NCHK), 256, 0, stream>>>(
            hn, lre + oHN, lim + oHN, bre + oHN, bim + oHN, ls + oH, f);
        p3_kernel<<<dim3(HD / 32, NCHK), 256, 0, stream>>>(
            hn, f, lre + oHN, lim + oHN, bre + oHN, bim + oHN,
            cre + oHN, cim + oHN, dd + oH, ls + oH, g);
        mm_kernel<<<dim3(HD / 64, LSEQ / 64), 256, 0, stream>>>(
            g, wb + lay * HH, wb + 4 * HH + lay * HH, ob + oH, o2b + oH, h);
    }
    dec_kernel<<<LSEQ, 192, 0, stream>>>(h, dw, db, (float*)d_out);
}

// Round 3
// 351.031 us; speedup vs baseline: 1.0419x; 1.0419x over previous
//
#include <hip/hip_runtime.h>
#include <hip/hip_bf16.h>
#include <math.h>

#define LSEQ 2048
#define HD   512
#define NST  32
#define LC   16
#define NCHK 128  /* LSEQ/LC */
#define HH   (HD * HD)

typedef __bf16 bf16;
typedef __bf16 bf16x8 __attribute__((ext_vector_type(8)));
typedef float  floatx4 __attribute__((ext_vector_type(4)));

__device__ __forceinline__ float wave_reduce_add(float v) {
#pragma unroll
    for (int m = 32; m; m >>= 1) v += __shfl_xor(v, m, 64);
    return v;
}

__device__ __forceinline__ float gelu_tanh(float x) {
    float z = 0.7978845608028654f * (x + 0.044715f * x * x * x);
    float e = __expf(2.f * z);
    float th = 1.f - 2.f / (e + 1.f);   // tanh(z), saturates cleanly at e=inf
    return 0.5f * x * (1.f + th);
}

__device__ __forceinline__ void make_ab(float lre, float lim, float step,
                                        float br0, float bi0,
                                        float& ar, float& ai, float& br, float& bi) {
    float s2 = 0.5f * step;
    float dr = 1.f - s2 * lre, di = -s2 * lim;      // 1 - (dt/2)Lam
    float inv = 1.f / (dr * dr + di * di);
    float blr = dr * inv, bli = -di * inv;          // BL = 1/(dr+i*di)
    float nr = 1.f + s2 * lre, ni = s2 * lim;       // 1 + (dt/2)Lam
    ar = blr * nr - bli * ni;
    ai = blr * ni + bli * nr;
    float tr = step * br0, ti = step * bi0;         // dt * B
    br = blr * tr - bli * ti;
    bi = blr * ti + bli * tr;
}

// ---------------- prep: coefficients for all 4 layers, transposed [lay][n][ch] ----------------
__global__ __launch_bounds__(256) void prep_kernel(
    const float* __restrict__ lre, const float* __restrict__ lim,
    const float* __restrict__ bre, const float* __restrict__ bim,
    const float* __restrict__ cre, const float* __restrict__ cim,
    const float* __restrict__ ls,
    float2* __restrict__ cA, float2* __restrict__ cB,
    float2* __restrict__ cC, float2* __restrict__ cAp) {
    int tid = blockIdx.x * 256 + threadIdx.x;       // 4*512*32 = 65536
    int lay = tid >> 14, rem = tid & 16383;
    int ch = rem >> 5, n = rem & 31;
    int src = tid;                                  // == ((lay*HD+ch)*NST + n)
    float step = __expf(ls[lay * HD + ch]);
    float ar, ai, br, bi;
    make_ab(lre[src], lim[src], step, bre[src], bim[src], ar, ai, br, bi);
    float xr = ar, xi = ai;                         // Abar^LC (LC=16 -> 4 squarings)
#pragma unroll
    for (int q = 0; q < 4; ++q) { float tt = xr * xr - xi * xi; xi = 2.f * xr * xi; xr = tt; }
    int dst = (lay * NST + n) * HD + ch;
    cA[dst]  = make_float2(ar, ai);
    cB[dst]  = make_float2(br, bi);
    cC[dst]  = make_float2(2.f * cre[src], 2.f * cim[src]);  // fold the 2x
    cAp[dst] = make_float2(xr, xi);
}

// ---------------- weight f32 -> bf16 conversion (out_w / out2_w) ----------------
__global__ __launch_bounds__(256) void cvt_kernel(
    const float* __restrict__ ow, const float* __restrict__ o2w,
    bf16* __restrict__ wb) {
    const float* src = blockIdx.y ? o2w : ow;
    bf16* dst = wb + blockIdx.y * (4 * HH);
    int i = (blockIdx.x * 256 + threadIdx.x) * 8;
    float4 a = *(const float4*)(src + i);
    float4 b = *(const float4*)(src + i + 4);
    bf16x8 o;
    o[0] = (bf16)a.x; o[1] = (bf16)a.y; o[2] = (bf16)a.z; o[3] = (bf16)a.w;
    o[4] = (bf16)b.x; o[5] = (bf16)b.y; o[6] = (bf16)b.z; o[7] = (bf16)b.w;
    *(bf16x8*)(dst + i) = o;
}

// ---------------- encoder ----------------
__global__ __launch_bounds__(256) void enc_kernel(
    const float* __restrict__ x, const float* __restrict__ w,
    const float* __restrict__ b, float* __restrict__ h) {
    int idx = blockIdx.x * 256 + threadIdx.x;   // t*HD + i
    int t = idx >> 9, i = idx & (HD - 1);
    float acc = b[i];
    float4 xv = *(const float4*)(x + t * 4);
    float4 wv = *(const float4*)(w + i * 4);
    acc = fmaf(xv.x, wv.x, acc);
    acc = fmaf(xv.y, wv.y, acc);
    acc = fmaf(xv.z, wv.z, acc);
    acc = fmaf(xv.w, wv.w, acc);
    h[idx] = acc;
}

// ---------------- LayerNorm: one wave per row ----------------
__global__ __launch_bounds__(256) void ln_kernel(
    const float* __restrict__ h, float* __restrict__ hn,
    const float* __restrict__ w, const float* __restrict__ b) {
    int wv = threadIdx.x >> 6, lane = threadIdx.x & 63;
    int row = blockIdx.x * 4 + wv;
    const float* hp = h + row * HD + lane * 8;
    float v[8];
    *(float4*)(v)     = *(const float4*)(hp);
    *(float4*)(v + 4) = *(const float4*)(hp + 4);
    float s = 0.f;
#pragma unroll
    for (int e = 0; e < 8; ++e) s += v[e];
    s = wave_reduce_add(s);
    float m = s * (1.f / HD);
    float q = 0.f;
#pragma unroll
    for (int e = 0; e < 8; ++e) { float d = v[e] - m; q += d * d; }
    q = wave_reduce_add(q);
    float rstd = rsqrtf(q * (1.f / HD) + 1e-5f);
    float w8[8], b8[8];
    *(float4*)(w8)     = *(const float4*)(w + lane * 8);
    *(float4*)(w8 + 4) = *(const float4*)(w + lane * 8 + 4);
    *(float4*)(b8)     = *(const float4*)(b + lane * 8);
    *(float4*)(b8 + 4) = *(const float4*)(b + lane * 8 + 4);
    float o[8];
#pragma unroll
    for (int e = 0; e < 8; ++e)
        o[e] = (v[e] - m) * rstd * w8[e] + b8[e];
    float* op = hn + row * HD + lane * 8;
    *(float4*)op       = *(float4*)o;
    *(float4*)(op + 4) = *(float4*)(o + 4);
}

// ---------------- P1: per-chunk local final states ----------------
// thread = (ch, sub, chunk): 16 states, no y. wave = 32 ch x 2 sub, fixed chunk.
__global__ __launch_bounds__(256, 1) void p1_kernel(
    const float* __restrict__ u,
    const float2* __restrict__ cA, const float2* __restrict__ cB,
    float2* __restrict__ f, int lay) {
    int lane = threadIdx.x & 63, w = threadIdx.x >> 6;
    int ch = blockIdx.x * 32 + (lane & 31);
    int sub = lane >> 5;
    int chunk = blockIdx.y * 4 + w;
    int cbase = (lay * NST + sub * 16) * HD + ch;
    float aR[16], aI[16], bR[16], bI[16];
#pragma unroll
    for (int j = 0; j < 16; ++j) {
        float2 t = cA[cbase + j * HD]; aR[j] = t.x; aI[j] = t.y;
        t = cB[cbase + j * HD];        bR[j] = t.x; bI[j] = t.y;
    }
    float sr[16], si[16];
#pragma unroll
    for (int j = 0; j < 16; ++j) { sr[j] = 0.f; si[j] = 0.f; }
    const float* up = u + chunk * LC * HD + ch;
#pragma unroll 4
    for (int t = 0; t < LC; ++t) {
        float uu = up[t * HD];
#pragma unroll
        for (int j = 0; j < 16; ++j) {
            float nr = fmaf(aR[j], sr[j], fmaf(-aI[j], si[j], bR[j] * uu));
            float ni = fmaf(aI[j], sr[j], fmaf( aR[j], si[j], bI[j] * uu));
            sr[j] = nr; si[j] = ni;
        }
    }
    float2* fp = f + (chunk * NST + sub * 16) * HD + ch;
#pragma unroll
    for (int j = 0; j < 16; ++j) fp[j * HD] = make_float2(sr[j], si[j]);
}

// ---------------- P2: in-place inclusive prefix scan over chunk states ----------------
// thread = (ch, n); s_c = Ap * s_{c-1} + f_c, f_c <- s_c
__global__ __launch_bounds__(64, 1) void p2_kernel(
    float2* __restrict__ f, const float2* __restrict__ cAp, int lay) {
    int ch = blockIdx.x * 64 + threadIdx.x;
    int n = blockIdx.y;
    float2 ap = cAp[(lay * NST + n) * HD + ch];
    float sr = 0.f, si = 0.f;
    float2* fp = f + n * HD + ch;
#pragma unroll 4
    for (int c = 0; c < NCHK; ++c) {
        float2 v = fp[(size_t)c * NST * HD];
        float nr = fmaf(ap.x, sr, fmaf(-ap.y, si, v.x));
        float ni = fmaf(ap.y, sr, fmaf( ap.x, si, v.y));
        sr = nr; si = ni;
        fp[(size_t)c * NST * HD] = make_float2(sr, si);
    }
}

// ---------------- P3: replay with carried init, emit gelu(y) as bf16 ----------------
__global__ __launch_bounds__(256, 1) void p3_kernel(
    const float* __restrict__ u, const float2* __restrict__ f,
    const float2* __restrict__ cA, const float2* __restrict__ cB,
    const float2* __restrict__ cC, const float* __restrict__ d_p,
    bf16* __restrict__ g, int lay) {
    int lane = threadIdx.x & 63, w = threadIdx.x >> 6;
    int ch = blockIdx.x * 32 + (lane & 31);
    int sub = lane >> 5;
    int chunk = blockIdx.y * 4 + w;
    int cbase = (lay * NST + sub * 16) * HD + ch;
    float aR[16], aI[16], bR[16], bI[16], cR[16], cI[16];
#pragma unroll
    for (int j = 0; j < 16; ++j) {
        float2 t = cA[cbase + j * HD]; aR[j] = t.x; aI[j] = t.y;
        t = cB[cbase + j * HD];        bR[j] = t.x; bI[j] = t.y;
        t = cC[cbase + j * HD];        cR[j] = t.x; cI[j] = t.y;
    }
    float dch = d_p[lay * HD + ch];
    float sr[16], si[16];
    if (chunk > 0) {
        const float2* ip = f + ((chunk - 1) * NST + sub * 16) * HD + ch;
#pragma unroll
        for (int j = 0; j < 16; ++j) { float2 v = ip[j * HD]; sr[j] = v.x; si[j] = v.y; }
    } else {
#pragma unroll
        for (int j = 0; j < 16; ++j) { sr[j] = 0.f; si[j] = 0.f; }
    }
    const float* up = u + chunk * LC * HD + ch;
    bf16* gp = g + chunk * LC * HD + ch;
#pragma unroll 4
    for (int t = 0; t < LC; ++t) {
        float uu = up[t * HD];
        float p = 0.f;
#pragma unroll
        for (int j = 0; j < 16; ++j) {
            float nr = fmaf(aR[j], sr[j], fmaf(-aI[j], si[j], bR[j] * uu));
            float ni = fmaf(aI[j], sr[j], fmaf( aR[j], si[j], bI[j] * uu));
            sr[j] = nr; si[j] = ni;
            p = fmaf(cR[j], nr, fmaf(-cI[j], ni, p));   // cC pre-scaled by 2
        }
        p += __shfl_xor(p, 32);
        float y = fmaf(dch, uu, p);
        if (sub == 0) gp[t * HD] = (bf16)gelu_tanh(y);
    }
}

// ---------------- fused gated dual-matmul + residual ----------------
__global__ __launch_bounds__(256) void mm_kernel(
    const bf16* __restrict__ A,    // g [L,H] bf16
    const bf16* __restrict__ W1,   // out_w  [H,H] (n,k) bf16
    const bf16* __restrict__ W2,   // out2_w [H,H] bf16
    const float* __restrict__ bias1, const float* __restrict__ bias2,
    float* __restrict__ Hio) {
    const int w = threadIdx.x >> 6, lane = threadIdx.x & 63;
    const int wm = w >> 1, wn = w & 1;
    const int mBase = blockIdx.y * 64 + wm * 32;
    const int nBase = blockIdx.x * 64 + wn * 32;
    const int lrow = lane & 15, quad = lane >> 4;

    floatx4 acc1[2][2] = {{{0.f,0.f,0.f,0.f},{0.f,0.f,0.f,0.f}},{{0.f,0.f,0.f,0.f},{0.f,0.f,0.f,0.f}}};
    floatx4 acc2[2][2] = {{{0.f,0.f,0.f,0.f},{0.f,0.f,0.f,0.f}},{{0.f,0.f,0.f,0.f},{0.f,0.f,0.f,0.f}}};

    for (int k0 = 0; k0 < HD; k0 += 32) {
        int kk = k0 + quad * 8;
        bf16x8 a0 = *(const bf16x8*)(A + (mBase + lrow) * HD + kk);
        bf16x8 a1 = *(const bf16x8*)(A + (mBase + 16 + lrow) * HD + kk);
        bf16x8 p0 = *(const bf16x8*)(W1 + (nBase + lrow) * HD + kk);
        bf16x8 p1 = *(const bf16x8*)(W1 + (nBase + 16 + lrow) * HD + kk);
        bf16x8 q0 = *(const bf16x8*)(W2 + (nBase + lrow) * HD + kk);
        bf16x8 q1 = *(const bf16x8*)(W2 + (nBase + 16 + lrow) * HD + kk);
        acc1[0][0] = __builtin_amdgcn_mfma_f32_16x16x32_bf16(a0, p0, acc1[0][0], 0, 0, 0);
        acc1[0][1] = __builtin_amdgcn_mfma_f32_16x16x32_bf16(a0, p1, acc1[0][1], 0, 0, 0);
        acc1[1][0] = __builtin_amdgcn_mfma_f32_16x16x32_bf16(a1, p0, acc1[1][0], 0, 0, 0);
        acc1[1][1] = __builtin_amdgcn_mfma_f32_16x16x32_bf16(a1, p1, acc1[1][1], 0, 0, 0);
        acc2[0][0] = __builtin_amdgcn_mfma_f32_16x16x32_bf16(a0, q0, acc2[0][0], 0, 0, 0);
        acc2[0][1] = __builtin_amdgcn_mfma_f32_16x16x32_bf16(a0, q1, acc2[0][1], 0, 0, 0);
        acc2[1][0] = __builtin_amdgcn_mfma_f32_16x16x32_bf16(a1, q0, acc2[1][0], 0, 0, 0);
        acc2[1][1] = __builtin_amdgcn_mfma_f32_16x16x32_bf16(a1, q1, acc2[1][1], 0, 0, 0);
    }

#pragma unroll
    for (int fm = 0; fm < 2; ++fm)
#pragma unroll
        for (int fn = 0; fn < 2; ++fn) {
            int j = nBase + fn * 16 + lrow;
            float bb1 = bias1[j], bb2 = bias2[j];
#pragma unroll
            for (int r = 0; r < 4; ++r) {
                int t = mBase + fm * 16 + quad * 4 + r;
                float z1 = acc1[fm][fn][r] + bb1;
                float z2 = acc2[fm][fn][r] + bb2;
                float val = z1 / (1.f + __expf(-z2));
                Hio[t * HD + j] += val;
            }
        }
}

// ---------------- decoder: out[L,3] ----------------
__global__ __launch_bounds__(192) void dec_kernel(
    const float* __restrict__ h, const float* __restrict__ w,
    const float* __restrict__ b, float* __restrict__ out) {
    int j = threadIdx.x >> 6, lane = threadIdx.x & 63;
    int t = blockIdx.x;
    const float* hp = h + t * HD + lane * 8;
    float v[8];
    *(float4*)(v)     = *(const float4*)(hp);
    *(float4*)(v + 4) = *(const float4*)(hp + 4);
    float w8[8];
    *(float4*)(w8)     = *(const float4*)(w + j * HD + lane * 8);
    *(float4*)(w8 + 4) = *(const float4*)(w + j * HD + lane * 8 + 4);
    float s = 0.f;
#pragma unroll
    for (int e = 0; e < 8; ++e) s = fmaf(v[e], w8[e], s);
    s = wave_reduce_add(s);
    if (lane == 0) out[t * 3 + j] = s + b[j];
}

extern "C" void kernel_launch(void* const* d_in, const int* in_sizes, int n_in,
                              void* d_out, int out_size, void* d_ws, size_t ws_size,
                              hipStream_t stream) {
    const float* x   = (const float*)d_in[0];
    const float* ew  = (const float*)d_in[1];
    const float* eb  = (const float*)d_in[2];
    const float* dw  = (const float*)d_in[3];
    const float* db  = (const float*)d_in[4];
    const float* nw  = (const float*)d_in[5];
    const float* nb  = (const float*)d_in[6];
    const float* lre = (const float*)d_in[7];
    const float* lim = (const float*)d_in[8];
    const float* bre = (const float*)d_in[9];
    const float* bim = (const float*)d_in[10];
    const float* cre = (const float*)d_in[11];
    const float* cim = (const float*)d_in[12];
    const float* dd  = (const float*)d_in[13];
    const float* ls  = (const float*)d_in[14];
    const float* ow  = (const float*)d_in[15];
    const float* ob  = (const float*)d_in[16];
    const float* o2w = (const float*)d_in[17];
    const float* o2b = (const float*)d_in[18];

    char* ws = (char*)d_ws;
    float*  h   = (float*)ws;                       // 4 MB  [L,H]
    float*  hn  = (float*)(ws + (4  << 20));        // 4 MB  [L,H]
    float2* f   = (float2*)(ws + (8  << 20));       // 16 MB [NCHK][NST][HD] float2
    bf16*   g   = (bf16*)(ws + (24 << 20));         // 2 MB  [L,H] bf16
    bf16*   wb  = (bf16*)(ws + (26 << 20));         // 4 MB  bf16 weights
    float2* cA  = (float2*)(ws + (30 << 20));       // 512 KB [4][NST][HD]
    float2* cB  = (float2*)(ws + (30 << 20) + (512 << 10));
    float2* cC  = (float2*)(ws + (31 << 20));
    float2* cAp = (float2*)(ws + (31 << 20) + (512 << 10));

    prep_kernel<<<256, 256, 0, stream>>>(lre, lim, bre, bim, cre, cim, ls, cA, cB, cC, cAp);
    cvt_kernel<<<dim3(4 * HH / (256 * 8), 2), 256, 0, stream>>>(ow, o2w, wb);
    enc_kernel<<<LSEQ * HD / 256, 256, 0, stream>>>(x, ew, eb, h);
    for (int lay = 0; lay < 4; ++lay) {
        int oH = lay * HD;
        ln_kernel<<<LSEQ / 4, 256, 0, stream>>>(h, hn, nw + oH, nb + oH);
        p1_kernel<<<dim3(HD / 32, NCHK / 4), 256, 0, stream>>>(hn, cA, cB, f, lay);
        p2_kernel<<<dim3(HD / 64, NST), 64, 0, stream>>>(f, cAp, lay);
        p3_kernel<<<dim3(HD / 32, NCHK / 4), 256, 0, stream>>>(hn, f, cA, cB, cC, dd, g, lay);
        mm_kernel<<<dim3(HD / 64, LSEQ / 64), 256, 0, stream>>>(
            g, wb + lay * HH, wb + 4 * HH + lay * HH, ob + oH, o2b + oH, h);
    }
    dec_kernel<<<LSEQ, 192, 0, stream>>>(h, dw, db, (float*)d_out);
}

// Round 4
// 343.146 us; speedup vs baseline: 1.0658x; 1.0230x over previous
//
#include <hip/hip_runtime.h>
#include <hip/hip_bf16.h>
#include <math.h>

#define LSEQ 2048
#define HD   512
#define NST  32
#define LC   16
#define NCHK 128  /* LSEQ/LC */
#define SUP  16   /* chunks per superchunk */
#define NSUP 8    /* NCHK/SUP */
#define HH   (HD * HD)

typedef __bf16 bf16;
typedef __bf16 bf16x8 __attribute__((ext_vector_type(8)));
typedef float  floatx4 __attribute__((ext_vector_type(4)));

__device__ __forceinline__ float wave_reduce_add(float v) {
#pragma unroll
    for (int m = 32; m; m >>= 1) v += __shfl_xor(v, m, 64);
    return v;
}

__device__ __forceinline__ float gelu_tanh(float x) {
    float z = 0.7978845608028654f * (x + 0.044715f * x * x * x);
    float e = __expf(2.f * z);
    float th = 1.f - 2.f / (e + 1.f);   // tanh(z), saturates cleanly at e=inf
    return 0.5f * x * (1.f + th);
}

__device__ __forceinline__ void make_ab(float lre, float lim, float step,
                                        float br0, float bi0,
                                        float& ar, float& ai, float& br, float& bi) {
    float s2 = 0.5f * step;
    float dr = 1.f - s2 * lre, di = -s2 * lim;      // 1 - (dt/2)Lam
    float inv = 1.f / (dr * dr + di * di);
    float blr = dr * inv, bli = -di * inv;          // BL = 1/(dr+i*di)
    float nr = 1.f + s2 * lre, ni = s2 * lim;       // 1 + (dt/2)Lam
    ar = blr * nr - bli * ni;
    ai = blr * ni + bli * nr;
    float tr = step * br0, ti = step * bi0;         // dt * B
    br = blr * tr - bli * ti;
    bi = blr * ti + bli * tr;
}

// ---------------- prep: coefficients for all 4 layers, transposed [lay][n][ch] ----------------
__global__ __launch_bounds__(256) void prep_kernel(
    const float* __restrict__ lre, const float* __restrict__ lim,
    const float* __restrict__ bre, const float* __restrict__ bim,
    const float* __restrict__ cre, const float* __restrict__ cim,
    const float* __restrict__ ls,
    float2* __restrict__ cA, float2* __restrict__ cB,
    float2* __restrict__ cC, float2* __restrict__ cAp) {
    int tid = blockIdx.x * 256 + threadIdx.x;       // 4*512*32 = 65536
    int lay = tid >> 14, rem = tid & 16383;
    int ch = rem >> 5, n = rem & 31;
    int src = tid;                                  // == ((lay*HD+ch)*NST + n)
    float step = __expf(ls[lay * HD + ch]);
    float ar, ai, br, bi;
    make_ab(lre[src], lim[src], step, bre[src], bim[src], ar, ai, br, bi);
    float xr = ar, xi = ai;                         // Abar^LC (LC=16 -> 4 squarings)
#pragma unroll
    for (int q = 0; q < 4; ++q) { float tt = xr * xr - xi * xi; xi = 2.f * xr * xi; xr = tt; }
    int dst = (lay * NST + n) * HD + ch;
    cA[dst]  = make_float2(ar, ai);
    cB[dst]  = make_float2(br, bi);
    cC[dst]  = make_float2(2.f * cre[src], 2.f * cim[src]);  // fold the 2x
    cAp[dst] = make_float2(xr, xi);
}

// ---------------- weight f32 -> bf16 conversion (out_w / out2_w) ----------------
__global__ __launch_bounds__(256) void cvt_kernel(
    const float* __restrict__ ow, const float* __restrict__ o2w,
    bf16* __restrict__ wb) {
    const float* src = blockIdx.y ? o2w : ow;
    bf16* dst = wb + blockIdx.y * (4 * HH);
    int i = (blockIdx.x * 256 + threadIdx.x) * 8;
    float4 a = *(const float4*)(src + i);
    float4 b = *(const float4*)(src + i + 4);
    bf16x8 o;
    o[0] = (bf16)a.x; o[1] = (bf16)a.y; o[2] = (bf16)a.z; o[3] = (bf16)a.w;
    o[4] = (bf16)b.x; o[5] = (bf16)b.y; o[6] = (bf16)b.z; o[7] = (bf16)b.w;
    *(bf16x8*)(dst + i) = o;
}

// ---------------- encoder ----------------
__global__ __launch_bounds__(256) void enc_kernel(
    const float* __restrict__ x, const float* __restrict__ w,
    const float* __restrict__ b, float* __restrict__ h) {
    int idx = blockIdx.x * 256 + threadIdx.x;   // t*HD + i
    int t = idx >> 9, i = idx & (HD - 1);
    float acc = b[i];
    float4 xv = *(const float4*)(x + t * 4);
    float4 wv = *(const float4*)(w + i * 4);
    acc = fmaf(xv.x, wv.x, acc);
    acc = fmaf(xv.y, wv.y, acc);
    acc = fmaf(xv.z, wv.z, acc);
    acc = fmaf(xv.w, wv.w, acc);
    h[idx] = acc;
}

// ---------------- LayerNorm: one wave per row ----------------
__global__ __launch_bounds__(256) void ln_kernel(
    const float* __restrict__ h, float* __restrict__ hn,
    const float* __restrict__ w, const float* __restrict__ b) {
    int wv = threadIdx.x >> 6, lane = threadIdx.x & 63;
    int row = blockIdx.x * 4 + wv;
    const float* hp = h + row * HD + lane * 8;
    float v[8];
    *(float4*)(v)     = *(const float4*)(hp);
    *(float4*)(v + 4) = *(const float4*)(hp + 4);
    float s = 0.f;
#pragma unroll
    for (int e = 0; e < 8; ++e) s += v[e];
    s = wave_reduce_add(s);
    float m = s * (1.f / HD);
    float q = 0.f;
#pragma unroll
    for (int e = 0; e < 8; ++e) { float d = v[e] - m; q += d * d; }
    q = wave_reduce_add(q);
    float rstd = rsqrtf(q * (1.f / HD) + 1e-5f);
    float w8[8], b8[8];
    *(float4*)(w8)     = *(const float4*)(w + lane * 8);
    *(float4*)(w8 + 4) = *(const float4*)(w + lane * 8 + 4);
    *(float4*)(b8)     = *(const float4*)(b + lane * 8);
    *(float4*)(b8 + 4) = *(const float4*)(b + lane * 8 + 4);
    float o[8];
#pragma unroll
    for (int e = 0; e < 8; ++e)
        o[e] = (v[e] - m) * rstd * w8[e] + b8[e];
    float* op = hn + row * HD + lane * 8;
    *(float4*)op       = *(float4*)o;
    *(float4*)(op + 4) = *(float4*)(o + 4);
}

// ---------------- P1: per-chunk local final states (8 states/lane, 4 lanes/ch) ----------------
__global__ __launch_bounds__(256, 4) void p1_kernel(
    const float* __restrict__ u,
    const float2* __restrict__ cA, const float2* __restrict__ cB,
    float2* __restrict__ f, int lay) {
    int lane = threadIdx.x & 63, w = threadIdx.x >> 6;
    int ch = blockIdx.x * 16 + (lane & 15);
    int sub = lane >> 4;                 // 0..3
    int chunk = blockIdx.y * 4 + w;
    int cbase = (lay * NST + sub * 8) * HD + ch;
    float aR[8], aI[8], bR[8], bI[8];
#pragma unroll
    for (int j = 0; j < 8; ++j) {
        float2 t = cA[cbase + j * HD]; aR[j] = t.x; aI[j] = t.y;
        t = cB[cbase + j * HD];        bR[j] = t.x; bI[j] = t.y;
    }
    float sr[8], si[8];
#pragma unroll
    for (int j = 0; j < 8; ++j) { sr[j] = 0.f; si[j] = 0.f; }
    const float* up = u + chunk * LC * HD + ch;
#pragma unroll 4
    for (int t = 0; t < LC; ++t) {
        float uu = up[t * HD];
#pragma unroll
        for (int j = 0; j < 8; ++j) {
            float nr = fmaf(aR[j], sr[j], fmaf(-aI[j], si[j], bR[j] * uu));
            float ni = fmaf(aI[j], sr[j], fmaf( aR[j], si[j], bI[j] * uu));
            sr[j] = nr; si[j] = ni;
        }
    }
    float2* fp = f + (chunk * NST + sub * 8) * HD + ch;
#pragma unroll
    for (int j = 0; j < 8; ++j) fp[j * HD] = make_float2(sr[j], si[j]);
}

// ---------------- P2a: local prefix scan within each superchunk (16 chunks) ----------------
__global__ __launch_bounds__(256) void p2a_kernel(
    float2* __restrict__ f, const float2* __restrict__ cAp, int lay) {
    int tg = blockIdx.x * 256 + threadIdx.x;    // 131072
    int ch = tg & 511;
    int ns = tg >> 9;                           // super*32 + n
    int n = ns & 31, sup = ns >> 5;
    float2 ap = cAp[(lay * NST + n) * HD + ch];
    float2* fp = f + ((sup * SUP) * NST + n) * HD + ch;
    float sr = 0.f, si = 0.f;
#pragma unroll 4
    for (int j = 0; j < SUP; ++j) {
        float2 v = fp[(size_t)j * NST * HD];
        float nr = fmaf(ap.x, sr, fmaf(-ap.y, si, v.x));
        float ni = fmaf(ap.y, sr, fmaf( ap.x, si, v.y));
        sr = nr; si = ni;
        fp[(size_t)j * NST * HD] = make_float2(sr, si);
    }
}

// ---------------- P2b: scan the 8 superchunk finals (positions c=16k+15) ----------------
__global__ __launch_bounds__(256) void p2b_kernel(
    float2* __restrict__ f, const float2* __restrict__ cAp, int lay) {
    int tg = blockIdx.x * 256 + threadIdx.x;    // 16384
    int ch = tg & 511, n = tg >> 9;
    float2 ap = cAp[(lay * NST + n) * HD + ch];
    float xr = ap.x, xi = ap.y;                 // ap^SUP (4 squarings)
#pragma unroll
    for (int q = 0; q < 4; ++q) { float tt = xr * xr - xi * xi; xi = 2.f * xr * xi; xr = tt; }
    float2* fp = f + ((SUP - 1) * NST + n) * HD + ch;
    const size_t stride = (size_t)SUP * NST * HD;
    float sr = 0.f, si = 0.f;
#pragma unroll
    for (int k = 0; k < NSUP; ++k) {
        float2 v = fp[k * stride];
        float nr = fmaf(xr, sr, fmaf(-xi, si, v.x));
        float ni = fmaf(xi, sr, fmaf( xr, si, v.y));
        sr = nr; si = ni;
        fp[k * stride] = make_float2(sr, si);
    }
}

// ---------------- P2c: apply superchunk carry to positions j=0..14 of supers k>=1 ----------------
__global__ __launch_bounds__(256) void p2c_kernel(
    float2* __restrict__ f, const float2* __restrict__ cAp, int lay) {
    int tg = blockIdx.x * 256 + threadIdx.x;    // 131072
    int ch = tg & 511;
    int ns = tg >> 9;
    int n = ns & 31, sup = ns >> 5;
    if (sup == 0) return;
    float2 ap = cAp[(lay * NST + n) * HD + ch];
    float2 S = f[((sup * SUP - 1) * NST + n) * HD + ch];   // global prefix at end of prev super
    float2* fp = f + ((sup * SUP) * NST + n) * HD + ch;
    float wr = ap.x, wi = ap.y;                 // A^(j+1), starts at A^1
#pragma unroll 4
    for (int j = 0; j < SUP - 1; ++j) {
        float2 v = fp[(size_t)j * NST * HD];
        v.x += wr * S.x - wi * S.y;
        v.y += wr * S.y + wi * S.x;
        fp[(size_t)j * NST * HD] = v;
        float nwr = wr * ap.x - wi * ap.y;
        float nwi = wr * ap.y + wi * ap.x;
        wr = nwr; wi = nwi;
    }
}

// ---------------- P3: replay with carried init, emit gelu(y) as bf16 ----------------
__global__ __launch_bounds__(256, 3) void p3_kernel(
    const float* __restrict__ u, const float2* __restrict__ f,
    const float2* __restrict__ cA, const float2* __restrict__ cB,
    const float2* __restrict__ cC, const float* __restrict__ d_p,
    bf16* __restrict__ g, int lay) {
    int lane = threadIdx.x & 63, w = threadIdx.x >> 6;
    int ch = blockIdx.x * 16 + (lane & 15);
    int sub = lane >> 4;                 // 0..3
    int chunk = blockIdx.y * 4 + w;
    int cbase = (lay * NST + sub * 8) * HD + ch;
    float aR[8], aI[8], bR[8], bI[8], cR[8], cI[8];
#pragma unroll
    for (int j = 0; j < 8; ++j) {
        float2 t = cA[cbase + j * HD]; aR[j] = t.x; aI[j] = t.y;
        t = cB[cbase + j * HD];        bR[j] = t.x; bI[j] = t.y;
        t = cC[cbase + j * HD];        cR[j] = t.x; cI[j] = t.y;
    }
    float dch = d_p[lay * HD + ch];
    float sr[8], si[8];
    if (chunk > 0) {
        const float2* ip = f + ((chunk - 1) * NST + sub * 8) * HD + ch;
#pragma unroll
        for (int j = 0; j < 8; ++j) { float2 v = ip[j * HD]; sr[j] = v.x; si[j] = v.y; }
    } else {
#pragma unroll
        for (int j = 0; j < 8; ++j) { sr[j] = 0.f; si[j] = 0.f; }
    }
    const float* up = u + chunk * LC * HD + ch;
    bf16* gp = g + chunk * LC * HD + ch;
#pragma unroll 4
    for (int t = 0; t < LC; ++t) {
        float uu = up[t * HD];
        float p = 0.f;
#pragma unroll
        for (int j = 0; j < 8; ++j) {
            float nr = fmaf(aR[j], sr[j], fmaf(-aI[j], si[j], bR[j] * uu));
            float ni = fmaf(aI[j], sr[j], fmaf( aR[j], si[j], bI[j] * uu));
            sr[j] = nr; si[j] = ni;
            p = fmaf(cR[j], nr, fmaf(-cI[j], ni, p));   // cC pre-scaled by 2
        }
        p += __shfl_xor(p, 16);
        p += __shfl_xor(p, 32);
        float y = fmaf(dch, uu, p);
        if (sub == 0) gp[t * HD] = (bf16)gelu_tanh(y);
    }
}

// ---------------- fused gated dual-matmul + residual ----------------
__global__ __launch_bounds__(256) void mm_kernel(
    const bf16* __restrict__ A,    // g [L,H] bf16
    const bf16* __restrict__ W1,   // out_w  [H,H] (n,k) bf16
    const bf16* __restrict__ W2,   // out2_w [H,H] bf16
    const float* __restrict__ bias1, const float* __restrict__ bias2,
    float* __restrict__ Hio) {
    const int w = threadIdx.x >> 6, lane = threadIdx.x & 63;
    const int wm = w >> 1, wn = w & 1;
    const int mBase = blockIdx.y * 64 + wm * 32;
    const int nBase = blockIdx.x * 64 + wn * 32;
    const int lrow = lane & 15, quad = lane >> 4;

    floatx4 acc1[2][2] = {{{0.f,0.f,0.f,0.f},{0.f,0.f,0.f,0.f}},{{0.f,0.f,0.f,0.f},{0.f,0.f,0.f,0.f}}};
    floatx4 acc2[2][2] = {{{0.f,0.f,0.f,0.f},{0.f,0.f,0.f,0.f}},{{0.f,0.f,0.f,0.f},{0.f,0.f,0.f,0.f}}};

    for (int k0 = 0; k0 < HD; k0 += 32) {
        int kk = k0 + quad * 8;
        bf16x8 a0 = *(const bf16x8*)(A + (mBase + lrow) * HD + kk);
        bf16x8 a1 = *(const bf16x8*)(A + (mBase + 16 + lrow) * HD + kk);
        bf16x8 p0 = *(const bf16x8*)(W1 + (nBase + lrow) * HD + kk);
        bf16x8 p1 = *(const bf16x8*)(W1 + (nBase + 16 + lrow) * HD + kk);
        bf16x8 q0 = *(const bf16x8*)(W2 + (nBase + lrow) * HD + kk);
        bf16x8 q1 = *(const bf16x8*)(W2 + (nBase + 16 + lrow) * HD + kk);
        acc1[0][0] = __builtin_amdgcn_mfma_f32_16x16x32_bf16(a0, p0, acc1[0][0], 0, 0, 0);
        acc1[0][1] = __builtin_amdgcn_mfma_f32_16x16x32_bf16(a0, p1, acc1[0][1], 0, 0, 0);
        acc1[1][0] = __builtin_amdgcn_mfma_f32_16x16x32_bf16(a1, p0, acc1[1][0], 0, 0, 0);
        acc1[1][1] = __builtin_amdgcn_mfma_f32_16x16x32_bf16(a1, p1, acc1[1][1], 0, 0, 0);
        acc2[0][0] = __builtin_amdgcn_mfma_f32_16x16x32_bf16(a0, q0, acc2[0][0], 0, 0, 0);
        acc2[0][1] = __builtin_amdgcn_mfma_f32_16x16x32_bf16(a0, q1, acc2[0][1], 0, 0, 0);
        acc2[1][0] = __builtin_amdgcn_mfma_f32_16x16x32_bf16(a1, q0, acc2[1][0], 0, 0, 0);
        acc2[1][1] = __builtin_amdgcn_mfma_f32_16x16x32_bf16(a1, q1, acc2[1][1], 0, 0, 0);
    }

#pragma unroll
    for (int fm = 0; fm < 2; ++fm)
#pragma unroll
        for (int fn = 0; fn < 2; ++fn) {
            int j = nBase + fn * 16 + lrow;
            float bb1 = bias1[j], bb2 = bias2[j];
#pragma unroll
            for (int r = 0; r < 4; ++r) {
                int t = mBase + fm * 16 + quad * 4 + r;
                float z1 = acc1[fm][fn][r] + bb1;
                float z2 = acc2[fm][fn][r] + bb2;
                float val = z1 / (1.f + __expf(-z2));
                Hio[t * HD + j] += val;
            }
        }
}

// ---------------- decoder: out[L,3] ----------------
__global__ __launch_bounds__(192) void dec_kernel(
    const float* __restrict__ h, const float* __restrict__ w,
    const float* __restrict__ b, float* __restrict__ out) {
    int j = threadIdx.x >> 6, lane = threadIdx.x & 63;
    int t = blockIdx.x;
    const float* hp = h + t * HD + lane * 8;
    float v[8];
    *(float4*)(v)     = *(const float4*)(hp);
    *(float4*)(v + 4) = *(const float4*)(hp + 4);
    float w8[8];
    *(float4*)(w8)     = *(const float4*)(w + j * HD + lane * 8);
    *(float4*)(w8 + 4) = *(const float4*)(w + j * HD + lane * 8 + 4);
    float s = 0.f;
#pragma unroll
    for (int e = 0; e < 8; ++e) s = fmaf(v[e], w8[e], s);
    s = wave_reduce_add(s);
    if (lane == 0) out[t * 3 + j] = s + b[j];
}

extern "C" void kernel_launch(void* const* d_in, const int* in_sizes, int n_in,
                              void* d_out, int out_size, void* d_ws, size_t ws_size,
                              hipStream_t stream) {
    const float* x   = (const float*)d_in[0];
    const float* ew  = (const float*)d_in[1];
    const float* eb  = (const float*)d_in[2];
    const float* dw  = (const float*)d_in[3];
    const float* db  = (const float*)d_in[4];
    const float* nw  = (const float*)d_in[5];
    const float* nb  = (const float*)d_in[6];
    const float* lre = (const float*)d_in[7];
    const float* lim = (const float*)d_in[8];
    const float* bre = (const float*)d_in[9];
    const float* bim = (const float*)d_in[10];
    const float* cre = (const float*)d_in[11];
    const float* cim = (const float*)d_in[12];
    const float* dd  = (const float*)d_in[13];
    const float* ls  = (const float*)d_in[14];
    const float* ow  = (const float*)d_in[15];
    const float* ob  = (const float*)d_in[16];
    const float* o2w = (const float*)d_in[17];
    const float* o2b = (const float*)d_in[18];

    char* ws = (char*)d_ws;
    float*  h   = (float*)ws;                       // 4 MB  [L,H]
    float*  hn  = (float*)(ws + (4  << 20));        // 4 MB  [L,H]
    float2* f   = (float2*)(ws + (8  << 20));       // 16 MB [NCHK][NST][HD] float2
    bf16*   g   = (bf16*)(ws + (24 << 20));         // 2 MB  [L,H] bf16
    bf16*   wb  = (bf16*)(ws + (26 << 20));         // 4 MB  bf16 weights
    float2* cA  = (float2*)(ws + (30 << 20));       // 512 KB [4][NST][HD]
    float2* cB  = (float2*)(ws + (30 << 20) + (512 << 10));
    float2* cC  = (float2*)(ws + (31 << 20));
    float2* cAp = (float2*)(ws + (31 << 20) + (512 << 10));

    prep_kernel<<<256, 256, 0, stream>>>(lre, lim, bre, bim, cre, cim, ls, cA, cB, cC, cAp);
    cvt_kernel<<<dim3(4 * HH / (256 * 8), 2), 256, 0, stream>>>(ow, o2w, wb);
    enc_kernel<<<LSEQ * HD / 256, 256, 0, stream>>>(x, ew, eb, h);
    for (int lay = 0; lay < 4; ++lay) {
        int oH = lay * HD;
        ln_kernel<<<LSEQ / 4, 256, 0, stream>>>(h, hn, nw + oH, nb + oH);
        p1_kernel<<<dim3(HD / 16, NCHK / 4), 256, 0, stream>>>(hn, cA, cB, f, lay);
        p2a_kernel<<<512, 256, 0, stream>>>(f, cAp, lay);
        p2b_kernel<<<64, 256, 0, stream>>>(f, cAp, lay);
        p2c_kernel<<<512, 256, 0, stream>>>(f, cAp, lay);
        p3_kernel<<<dim3(HD / 16, NCHK / 4), 256, 0, stream>>>(hn, f, cA, cB, cC, dd, g, lay);
        mm_kernel<<<dim3(HD / 64, LSEQ / 64), 256, 0, stream>>>(
            g, wb + lay * HH, wb + 4 * HH + lay * HH, ob + oH, o2b + oH, h);
    }
    dec_kernel<<<LSEQ, 192, 0, stream>>>(h, dw, db, (float*)d_out);
}

// Round 5
// 315.155 us; speedup vs baseline: 1.1605x; 1.0888x over previous
//
#include <hip/hip_runtime.h>
#include <hip/hip_bf16.h>
#include <math.h>

#define LSEQ 2048
#define HD   512
#define NST  32
#define LC   32
#define NCHK 64   /* LSEQ/LC */
#define SUP  8    /* chunks per superchunk */
#define NSUP 8    /* NCHK/SUP */
#define HH   (HD * HD)

typedef __bf16 bf16;
typedef __bf16 bf16x8 __attribute__((ext_vector_type(8)));
typedef float  floatx4 __attribute__((ext_vector_type(4)));

__device__ __forceinline__ float wave_reduce_add(float v) {
#pragma unroll
    for (int m = 32; m; m >>= 1) v += __shfl_xor(v, m, 64);
    return v;
}

__device__ __forceinline__ float gelu_tanh(float x) {
    float z = 0.7978845608028654f * (x + 0.044715f * x * x * x);
    float e = __expf(2.f * z);
    float th = 1.f - 2.f / (e + 1.f);   // tanh(z), saturates cleanly at e=inf
    return 0.5f * x * (1.f + th);
}

__device__ __forceinline__ void make_ab(float lre, float lim, float step,
                                        float br0, float bi0,
                                        float& ar, float& ai, float& br, float& bi) {
    float s2 = 0.5f * step;
    float dr = 1.f - s2 * lre, di = -s2 * lim;      // 1 - (dt/2)Lam
    float inv = 1.f / (dr * dr + di * di);
    float blr = dr * inv, bli = -di * inv;          // BL = 1/(dr+i*di)
    float nr = 1.f + s2 * lre, ni = s2 * lim;       // 1 + (dt/2)Lam
    ar = blr * nr - bli * ni;
    ai = blr * ni + bli * nr;
    float tr = step * br0, ti = step * bi0;         // dt * B
    br = blr * tr - bli * ti;
    bi = blr * ti + bli * tr;
}

// ---------------- prep: coefficients for all 4 layers, transposed [lay][n][ch] ----------------
__global__ __launch_bounds__(256) void prep_kernel(
    const float* __restrict__ lre, const float* __restrict__ lim,
    const float* __restrict__ bre, const float* __restrict__ bim,
    const float* __restrict__ cre, const float* __restrict__ cim,
    const float* __restrict__ ls,
    float2* __restrict__ cA, float2* __restrict__ cB,
    float2* __restrict__ cC, float2* __restrict__ cAp) {
    int tid = blockIdx.x * 256 + threadIdx.x;       // 4*512*32 = 65536
    int lay = tid >> 14, rem = tid & 16383;
    int ch = rem >> 5, n = rem & 31;
    int src = tid;                                  // == ((lay*HD+ch)*NST + n)
    float step = __expf(ls[lay * HD + ch]);
    float ar, ai, br, bi;
    make_ab(lre[src], lim[src], step, bre[src], bim[src], ar, ai, br, bi);
    float xr = ar, xi = ai;                         // Abar^LC (LC=32 -> 5 squarings)
#pragma unroll
    for (int q = 0; q < 5; ++q) { float tt = xr * xr - xi * xi; xi = 2.f * xr * xi; xr = tt; }
    int dst = (lay * NST + n) * HD + ch;
    cA[dst]  = make_float2(ar, ai);
    cB[dst]  = make_float2(br, bi);
    cC[dst]  = make_float2(2.f * cre[src], 2.f * cim[src]);  // fold the 2x
    cAp[dst] = make_float2(xr, xi);
}

// ---------------- weight f32 -> bf16 conversion (out_w / out2_w) ----------------
__global__ __launch_bounds__(256) void cvt_kernel(
    const float* __restrict__ ow, const float* __restrict__ o2w,
    bf16* __restrict__ wb) {
    const float* src = blockIdx.y ? o2w : ow;
    bf16* dst = wb + blockIdx.y * (4 * HH);
    int i = (blockIdx.x * 256 + threadIdx.x) * 8;
    float4 a = *(const float4*)(src + i);
    float4 b = *(const float4*)(src + i + 4);
    bf16x8 o;
    o[0] = (bf16)a.x; o[1] = (bf16)a.y; o[2] = (bf16)a.z; o[3] = (bf16)a.w;
    o[4] = (bf16)b.x; o[5] = (bf16)b.y; o[6] = (bf16)b.z; o[7] = (bf16)b.w;
    *(bf16x8*)(dst + i) = o;
}

// ---------------- encoder ----------------
__global__ __launch_bounds__(256) void enc_kernel(
    const float* __restrict__ x, const float* __restrict__ w,
    const float* __restrict__ b, float* __restrict__ h) {
    int idx = blockIdx.x * 256 + threadIdx.x;   // t*HD + i
    int t = idx >> 9, i = idx & (HD - 1);
    float acc = b[i];
    float4 xv = *(const float4*)(x + t * 4);
    float4 wv = *(const float4*)(w + i * 4);
    acc = fmaf(xv.x, wv.x, acc);
    acc = fmaf(xv.y, wv.y, acc);
    acc = fmaf(xv.z, wv.z, acc);
    acc = fmaf(xv.w, wv.w, acc);
    h[idx] = acc;
}

// ---------------- LayerNorm: one wave per row ----------------
__global__ __launch_bounds__(256) void ln_kernel(
    const float* __restrict__ h, float* __restrict__ hn,
    const float* __restrict__ w, const float* __restrict__ b) {
    int wv = threadIdx.x >> 6, lane = threadIdx.x & 63;
    int row = blockIdx.x * 4 + wv;
    const float* hp = h + row * HD + lane * 8;
    float v[8];
    *(float4*)(v)     = *(const float4*)(hp);
    *(float4*)(v + 4) = *(const float4*)(hp + 4);
    float s = 0.f;
#pragma unroll
    for (int e = 0; e < 8; ++e) s += v[e];
    s = wave_reduce_add(s);
    float m = s * (1.f / HD);
    float q = 0.f;
#pragma unroll
    for (int e = 0; e < 8; ++e) { float d = v[e] - m; q += d * d; }
    q = wave_reduce_add(q);
    float rstd = rsqrtf(q * (1.f / HD) + 1e-5f);
    float w8[8], b8[8];
    *(float4*)(w8)     = *(const float4*)(w + lane * 8);
    *(float4*)(w8 + 4) = *(const float4*)(w + lane * 8 + 4);
    *(float4*)(b8)     = *(const float4*)(b + lane * 8);
    *(float4*)(b8 + 4) = *(const float4*)(b + lane * 8 + 4);
    float o[8];
#pragma unroll
    for (int e = 0; e < 8; ++e)
        o[e] = (v[e] - m) * rstd * w8[e] + b8[e];
    float* op = hn + row * HD + lane * 8;
    *(float4*)op       = *(float4*)o;
    *(float4*)(op + 4) = *(float4*)(o + 4);
}

// ---------------- P1: per-chunk local final states, u staged through LDS ----------------
// block: 16 ch x 4 chunks (one per wave); lane: 16 ch x 4 sub(8 states each)
__global__ __launch_bounds__(256, 2) void p1_kernel(
    const float* __restrict__ u,
    const float2* __restrict__ cA, const float2* __restrict__ cB,
    float2* __restrict__ f, int lay) {
    __shared__ float tile[4 * LC * 16];             // 8 KB: 128 t-rows x 16 ch
    int tid = threadIdx.x;
    int lane = tid & 63, w = tid >> 6;
    int chl = lane & 15;
    int ch = blockIdx.x * 16 + chl;
    int sub = lane >> 4;                            // 0..3
    int chunk = blockIdx.y * 4 + w;
    // cooperative tile load: rows t0..t0+127, cols bx*16..+15
    int t0 = blockIdx.y * 4 * LC;
    const float* ub = u + (size_t)t0 * HD + blockIdx.x * 16;
#pragma unroll
    for (int r = 0; r < 8; ++r) {
        int idx = r * 256 + tid;
        tile[idx] = ub[(idx >> 4) * HD + (idx & 15)];
    }
    int cbase = (lay * NST + sub * 8) * HD + ch;
    float aR[8], aI[8], bR[8], bI[8];
#pragma unroll
    for (int j = 0; j < 8; ++j) {
        float2 t = cA[cbase + j * HD]; aR[j] = t.x; aI[j] = t.y;
        t = cB[cbase + j * HD];        bR[j] = t.x; bI[j] = t.y;
    }
    float sr[8], si[8];
#pragma unroll
    for (int j = 0; j < 8; ++j) { sr[j] = 0.f; si[j] = 0.f; }
    __syncthreads();
    const float* tp = tile + (w * LC) * 16 + chl;
#pragma unroll 4
    for (int t = 0; t < LC; ++t) {
        float uu = tp[t * 16];
#pragma unroll
        for (int j = 0; j < 8; ++j) {
            float nr = fmaf(aR[j], sr[j], fmaf(-aI[j], si[j], bR[j] * uu));
            float ni = fmaf(aI[j], sr[j], fmaf( aR[j], si[j], bI[j] * uu));
            sr[j] = nr; si[j] = ni;
        }
    }
    float2* fp = f + (chunk * NST + sub * 8) * HD + ch;
#pragma unroll
    for (int j = 0; j < 8; ++j) fp[j * HD] = make_float2(sr[j], si[j]);
}

// ---------------- P2a: local prefix scan within each superchunk (8 chunks) ----------------
__global__ __launch_bounds__(256) void p2a_kernel(
    float2* __restrict__ f, const float2* __restrict__ cAp, int lay) {
    int tg = blockIdx.x * 256 + threadIdx.x;    // 512*32*8 = 131072
    int ch = tg & 511;
    int ns = tg >> 9;                           // sup*32 + n
    int n = ns & 31, sup = ns >> 5;
    float2 ap = cAp[(lay * NST + n) * HD + ch];
    float2* fp = f + ((sup * SUP) * NST + n) * HD + ch;
    float sr = 0.f, si = 0.f;
#pragma unroll
    for (int j = 0; j < SUP; ++j) {
        float2 v = fp[(size_t)j * NST * HD];
        float nr = fmaf(ap.x, sr, fmaf(-ap.y, si, v.x));
        float ni = fmaf(ap.y, sr, fmaf( ap.x, si, v.y));
        sr = nr; si = ni;
        fp[(size_t)j * NST * HD] = make_float2(sr, si);
    }
}

// ---------------- P2b: scan the 8 superchunk finals (positions c=8k+7) ----------------
__global__ __launch_bounds__(256) void p2b_kernel(
    float2* __restrict__ f, const float2* __restrict__ cAp, int lay) {
    int tg = blockIdx.x * 256 + threadIdx.x;    // 16384
    int ch = tg & 511, n = tg >> 9;
    float2 ap = cAp[(lay * NST + n) * HD + ch];
    float xr = ap.x, xi = ap.y;                 // ap^SUP (3 squarings)
#pragma unroll
    for (int q = 0; q < 3; ++q) { float tt = xr * xr - xi * xi; xi = 2.f * xr * xi; xr = tt; }
    float2* fp = f + ((SUP - 1) * NST + n) * HD + ch;
    const size_t stride = (size_t)SUP * NST * HD;
    float sr = 0.f, si = 0.f;
#pragma unroll
    for (int k = 0; k < NSUP; ++k) {
        float2 v = fp[k * stride];
        float nr = fmaf(xr, sr, fmaf(-xi, si, v.x));
        float ni = fmaf(xi, sr, fmaf( xr, si, v.y));
        sr = nr; si = ni;
        fp[k * stride] = make_float2(sr, si);
    }
}

// ---------------- P2c: apply superchunk carry to positions j=0..SUP-2 of supers k>=1 ----------------
__global__ __launch_bounds__(256) void p2c_kernel(
    float2* __restrict__ f, const float2* __restrict__ cAp, int lay) {
    int tg = blockIdx.x * 256 + threadIdx.x;    // 131072
    int ch = tg & 511;
    int ns = tg >> 9;
    int n = ns & 31, sup = ns >> 5;
    if (sup == 0) return;
    float2 ap = cAp[(lay * NST + n) * HD + ch];
    float2 S = f[((sup * SUP - 1) * NST + n) * HD + ch];   // global prefix at end of prev super
    float2* fp = f + ((sup * SUP) * NST + n) * HD + ch;
    float wr = ap.x, wi = ap.y;                 // A^(j+1)*LC weights via cAp powers
#pragma unroll
    for (int j = 0; j < SUP - 1; ++j) {
        float2 v = fp[(size_t)j * NST * HD];
        v.x += wr * S.x - wi * S.y;
        v.y += wr * S.y + wi * S.x;
        fp[(size_t)j * NST * HD] = v;
        float nwr = wr * ap.x - wi * ap.y;
        float nwi = wr * ap.y + wi * ap.x;
        wr = nwr; wi = nwi;
    }
}

// ---------------- P3: replay with carried init (LDS-staged u), emit gelu(y) as bf16 ----------------
__global__ __launch_bounds__(256, 2) void p3_kernel(
    const float* __restrict__ u, const float2* __restrict__ f,
    const float2* __restrict__ cA, const float2* __restrict__ cB,
    const float2* __restrict__ cC, const float* __restrict__ d_p,
    bf16* __restrict__ g, int lay) {
    __shared__ float tile[4 * LC * 16];             // 8 KB
    int tid = threadIdx.x;
    int lane = tid & 63, w = tid >> 6;
    int chl = lane & 15;
    int ch = blockIdx.x * 16 + chl;
    int sub = lane >> 4;
    int chunk = blockIdx.y * 4 + w;
    int t0 = blockIdx.y * 4 * LC;
    const float* ub = u + (size_t)t0 * HD + blockIdx.x * 16;
#pragma unroll
    for (int r = 0; r < 8; ++r) {
        int idx = r * 256 + tid;
        tile[idx] = ub[(idx >> 4) * HD + (idx & 15)];
    }
    int cbase = (lay * NST + sub * 8) * HD + ch;
    float aR[8], aI[8], bR[8], bI[8], cR[8], cI[8];
#pragma unroll
    for (int j = 0; j < 8; ++j) {
        float2 t = cA[cbase + j * HD]; aR[j] = t.x; aI[j] = t.y;
        t = cB[cbase + j * HD];        bR[j] = t.x; bI[j] = t.y;
        t = cC[cbase + j * HD];        cR[j] = t.x; cI[j] = t.y;
    }
    float dch = d_p[lay * HD + ch];
    float sr[8], si[8];
    if (chunk > 0) {
        const float2* ip = f + ((chunk - 1) * NST + sub * 8) * HD + ch;
#pragma unroll
        for (int j = 0; j < 8; ++j) { float2 v = ip[j * HD]; sr[j] = v.x; si[j] = v.y; }
    } else {
#pragma unroll
        for (int j = 0; j < 8; ++j) { sr[j] = 0.f; si[j] = 0.f; }
    }
    __syncthreads();
    const float* tp = tile + (w * LC) * 16 + chl;
    bf16* gp = g + (size_t)chunk * LC * HD + ch;
#pragma unroll 4
    for (int t = 0; t < LC; ++t) {
        float uu = tp[t * 16];
        float p = 0.f;
#pragma unroll
        for (int j = 0; j < 8; ++j) {
            float nr = fmaf(aR[j], sr[j], fmaf(-aI[j], si[j], bR[j] * uu));
            float ni = fmaf(aI[j], sr[j], fmaf( aR[j], si[j], bI[j] * uu));
            sr[j] = nr; si[j] = ni;
            p = fmaf(cR[j], nr, fmaf(-cI[j], ni, p));   // cC pre-scaled by 2
        }
        p += __shfl_xor(p, 16);
        p += __shfl_xor(p, 32);
        float y = fmaf(dch, uu, p);
        if (sub == 0) gp[t * HD] = (bf16)gelu_tanh(y);
    }
}

// ---------------- fused gated dual-matmul + residual ----------------
__global__ __launch_bounds__(256) void mm_kernel(
    const bf16* __restrict__ A,    // g [L,H] bf16
    const bf16* __restrict__ W1,   // out_w  [H,H] (n,k) bf16
    const bf16* __restrict__ W2,   // out2_w [H,H] bf16
    const float* __restrict__ bias1, const float* __restrict__ bias2,
    float* __restrict__ Hio) {
    const int w = threadIdx.x >> 6, lane = threadIdx.x & 63;
    const int wm = w >> 1, wn = w & 1;
    const int mBase = blockIdx.y * 64 + wm * 32;
    const int nBase = blockIdx.x * 64 + wn * 32;
    const int lrow = lane & 15, quad = lane >> 4;

    floatx4 acc1[2][2] = {{{0.f,0.f,0.f,0.f},{0.f,0.f,0.f,0.f}},{{0.f,0.f,0.f,0.f},{0.f,0.f,0.f,0.f}}};
    floatx4 acc2[2][2] = {{{0.f,0.f,0.f,0.f},{0.f,0.f,0.f,0.f}},{{0.f,0.f,0.f,0.f},{0.f,0.f,0.f,0.f}}};

    for (int k0 = 0; k0 < HD; k0 += 32) {
        int kk = k0 + quad * 8;
        bf16x8 a0 = *(const bf16x8*)(A + (mBase + lrow) * HD + kk);
        bf16x8 a1 = *(const bf16x8*)(A + (mBase + 16 + lrow) * HD + kk);
        bf16x8 p0 = *(const bf16x8*)(W1 + (nBase + lrow) * HD + kk);
        bf16x8 p1 = *(const bf16x8*)(W1 + (nBase + 16 + lrow) * HD + kk);
        bf16x8 q0 = *(const bf16x8*)(W2 + (nBase + lrow) * HD + kk);
        bf16x8 q1 = *(const bf16x8*)(W2 + (nBase + 16 + lrow) * HD + kk);
        acc1[0][0] = __builtin_amdgcn_mfma_f32_16x16x32_bf16(a0, p0, acc1[0][0], 0, 0, 0);
        acc1[0][1] = __builtin_amdgcn_mfma_f32_16x16x32_bf16(a0, p1, acc1[0][1], 0, 0, 0);
        acc1[1][0] = __builtin_amdgcn_mfma_f32_16x16x32_bf16(a1, p0, acc1[1][0], 0, 0, 0);
        acc1[1][1] = __builtin_amdgcn_mfma_f32_16x16x32_bf16(a1, p1, acc1[1][1], 0, 0, 0);
        acc2[0][0] = __builtin_amdgcn_mfma_f32_16x16x32_bf16(a0, q0, acc2[0][0], 0, 0, 0);
        acc2[0][1] = __builtin_amdgcn_mfma_f32_16x16x32_bf16(a0, q1, acc2[0][1], 0, 0, 0);
        acc2[1][0] = __builtin_amdgcn_mfma_f32_16x16x32_bf16(a1, q0, acc2[1][0], 0, 0, 0);
        acc2[1][1] = __builtin_amdgcn_mfma_f32_16x16x32_bf16(a1, q1, acc2[1][1], 0, 0, 0);
    }

#pragma unroll
    for (int fm = 0; fm < 2; ++fm)
#pragma unroll
        for (int fn = 0; fn < 2; ++fn) {
            int j = nBase + fn * 16 + lrow;
            float bb1 = bias1[j], bb2 = bias2[j];
#pragma unroll
            for (int r = 0; r < 4; ++r) {
                int t = mBase + fm * 16 + quad * 4 + r;
                float z1 = acc1[fm][fn][r] + bb1;
                float z2 = acc2[fm][fn][r] + bb2;
                float val = z1 / (1.f + __expf(-z2));
                Hio[t * HD + j] += val;
            }
        }
}

// ---------------- decoder: out[L,3] ----------------
__global__ __launch_bounds__(192) void dec_kernel(
    const float* __restrict__ h, const float* __restrict__ w,
    const float* __restrict__ b, float* __restrict__ out) {
    int j = threadIdx.x >> 6, lane = threadIdx.x & 63;
    int t = blockIdx.x;
    const float* hp = h + t * HD + lane * 8;
    float v[8];
    *(float4*)(v)     = *(const float4*)(hp);
    *(float4*)(v + 4) = *(const float4*)(hp + 4);
    float w8[8];
    *(float4*)(w8)     = *(const float4*)(w + j * HD + lane * 8);
    *(float4*)(w8 + 4) = *(const float4*)(w + j * HD + lane * 8 + 4);
    float s = 0.f;
#pragma unroll
    for (int e = 0; e < 8; ++e) s = fmaf(v[e], w8[e], s);
    s = wave_reduce_add(s);
    if (lane == 0) out[t * 3 + j] = s + b[j];
}

extern "C" void kernel_launch(void* const* d_in, const int* in_sizes, int n_in,
                              void* d_out, int out_size, void* d_ws, size_t ws_size,
                              hipStream_t stream) {
    const float* x   = (const float*)d_in[0];
    const float* ew  = (const float*)d_in[1];
    const float* eb  = (const float*)d_in[2];
    const float* dw  = (const float*)d_in[3];
    const float* db  = (const float*)d_in[4];
    const float* nw  = (const float*)d_in[5];
    const float* nb  = (const float*)d_in[6];
    const float* lre = (const float*)d_in[7];
    const float* lim = (const float*)d_in[8];
    const float* bre = (const float*)d_in[9];
    const float* bim = (const float*)d_in[10];
    const float* cre = (const float*)d_in[11];
    const float* cim = (const float*)d_in[12];
    const float* dd  = (const float*)d_in[13];
    const float* ls  = (const float*)d_in[14];
    const float* ow  = (const float*)d_in[15];
    const float* ob  = (const float*)d_in[16];
    const float* o2w = (const float*)d_in[17];
    const float* o2b = (const float*)d_in[18];

    char* ws = (char*)d_ws;
    float*  h   = (float*)ws;                       // 4 MB  [L,H]
    float*  hn  = (float*)(ws + (4  << 20));        // 4 MB  [L,H]
    float2* f   = (float2*)(ws + (8  << 20));       // 8.4 MB [NCHK][NST][HD] float2
    bf16*   g   = (bf16*)(ws + (24 << 20));         // 2 MB  [L,H] bf16
    bf16*   wb  = (bf16*)(ws + (26 << 20));         // 4 MB  bf16 weights
    float2* cA  = (float2*)(ws + (30 << 20));       // 512 KB [4][NST][HD]
    float2* cB  = (float2*)(ws + (30 << 20) + (512 << 10));
    float2* cC  = (float2*)(ws + (31 << 20));
    float2* cAp = (float2*)(ws + (31 << 20) + (512 << 10));

    prep_kernel<<<256, 256, 0, stream>>>(lre, lim, bre, bim, cre, cim, ls, cA, cB, cC, cAp);
    cvt_kernel<<<dim3(4 * HH / (256 * 8), 2), 256, 0, stream>>>(ow, o2w, wb);
    enc_kernel<<<LSEQ * HD / 256, 256, 0, stream>>>(x, ew, eb, h);
    for (int lay = 0; lay < 4; ++lay) {
        int oH = lay * HD;
        ln_kernel<<<LSEQ / 4, 256, 0, stream>>>(h, hn, nw + oH, nb + oH);
        p1_kernel<<<dim3(HD / 16, NCHK / 4), 256, 0, stream>>>(hn, cA, cB, f, lay);
        p2a_kernel<<<512, 256, 0, stream>>>(f, cAp, lay);
        p2b_kernel<<<64, 256, 0, stream>>>(f, cAp, lay);
        p2c_kernel<<<512, 256, 0, stream>>>(f, cAp, lay);
        p3_kernel<<<dim3(HD / 16, NCHK / 4), 256, 0, stream>>>(hn, f, cA, cB, cC, dd, g, lay);
        mm_kernel<<<dim3(HD / 64, LSEQ / 64), 256, 0, stream>>>(
            g, wb + lay * HH, wb + 4 * HH + lay * HH, ob + oH, o2b + oH, h);
    }
    dec_kernel<<<LSEQ, 192, 0, stream>>>(h, dw, db, (float*)d_out);
}